// Round 1
// baseline (2378.249 us; speedup 1.0000x reference)
//
#include <hip/hip_runtime.h>
#include <stdint.h>

typedef unsigned short u16;
typedef __attribute__((ext_vector_type(8))) short short8;
typedef __attribute__((ext_vector_type(4))) float f32x4;

#define T_TOK 4096
#define H_DIM 2048
#define E_NUM 32
#define I_DIM 1024
#define IS_DIM 2048
#define TOPK 8
#define NGRP 8
#define TOPG 4
#define EPG (E_NUM / NGRP)
#define RSCALE 2.5f
#define NPAIR (T_TOK * TOPK)

#define BM 128
#define BN 128
#define BK 64

// ---------- helpers ----------

__device__ __forceinline__ u16 f2bf(float f) {
  uint32_t x = __float_as_uint(f);
  uint32_t r = (x + 0x7fffu + ((x >> 16) & 1u)) >> 16;  // RNE
  return (u16)r;
}

__device__ __forceinline__ void gll16(const void* g, void* l) {
  __builtin_amdgcn_global_load_lds(
      (const __attribute__((address_space(1))) void*)g,
      (__attribute__((address_space(3))) void*)l, 16, 0, 0);
}

// ---------- fp32 -> bf16 conversion ----------

__global__ void cvt_kernel(const float* __restrict__ in, u16* __restrict__ out, int n4) {
  int i = blockIdx.x * blockDim.x + threadIdx.x;
  int stride = gridDim.x * blockDim.x;
  for (; i < n4; i += stride) {
    float4 v = reinterpret_cast<const float4*>(in)[i];
    ushort4 o;
    o.x = f2bf(v.x); o.y = f2bf(v.y); o.z = f2bf(v.z); o.w = f2bf(v.w);
    reinterpret_cast<ushort4*>(out)[i] = o;
  }
}

// ---------- router: logits = x @ gate_w.T (fp64 accumulate for exact top-k) ----------

__global__ __launch_bounds__(256) void router_kernel(const float* __restrict__ x,
                                                     const float* __restrict__ gw,
                                                     float* __restrict__ logits) {
  __shared__ float xs[H_DIM];
  int t = blockIdx.x;
  const float* xr = x + (long)t * H_DIM;
  for (int k = threadIdx.x; k < H_DIM; k += 256) xs[k] = xr[k];
  __syncthreads();
  int e = threadIdx.x >> 3;
  int j = threadIdx.x & 7;
  const float* w = gw + (long)e * H_DIM;
  double acc = 0.0;
  for (int k = j; k < H_DIM; k += 8) acc += (double)xs[k] * (double)w[k];
  acc += __shfl_down(acc, 4, 8);
  acc += __shfl_down(acc, 2, 8);
  acc += __shfl_down(acc, 1, 8);
  if (j == 0) logits[t * E_NUM + e] = (float)acc;
}

// ---------- per-token routing: grouped top-k, DeepSeek-V3 semantics ----------

__global__ void zero_kernel(int* counts) {
  int i = threadIdx.x;
  if (i < E_NUM) counts[i] = 0;
}

__global__ void routing_kernel(const float* __restrict__ logits,
                               const float* __restrict__ ebias,
                               int* __restrict__ tk_idx, float* __restrict__ tk_w,
                               int* __restrict__ counts) {
  int t = blockIdx.x * blockDim.x + threadIdx.x;
  if (t >= T_TOK) return;
  float sc[E_NUM], swb[E_NUM];
  for (int e = 0; e < E_NUM; e++) {
    float l = logits[t * E_NUM + e];
    float s = 1.0f / (1.0f + expf(-l));
    sc[e] = s;
    swb[e] = s + ebias[e];
  }
  // group scores = sum of top-2 per group of EPG consecutive experts
  float gs[NGRP];
  for (int g = 0; g < NGRP; g++) {
    float m1 = -3e38f, m2 = -3e38f;
    for (int i = 0; i < EPG; i++) {
      float v = swb[g * EPG + i];
      if (v > m1) { m2 = m1; m1 = v; }
      else if (v > m2) { m2 = v; }
    }
    gs[g] = m1 + m2;
  }
  // top TOPG groups (tie -> lower index, matching lax.top_k stability)
  bool gmask[NGRP];
  for (int g = 0; g < NGRP; g++) gmask[g] = false;
  for (int k = 0; k < TOPG; k++) {
    int best = 0; float bv = -3e38f;
    for (int g = 0; g < NGRP; g++)
      if (!gmask[g] && gs[g] > bv) { bv = gs[g]; best = g; }
    gmask[best] = true;
  }
  // top TOPK experts among allowed groups
  bool taken[E_NUM];
  for (int e = 0; e < E_NUM; e++) taken[e] = false;
  int idx[TOPK]; float wv[TOPK]; float wsum = 0.0f;
  for (int k = 0; k < TOPK; k++) {
    int best = 0; float bv = -3e38f;
    for (int e = 0; e < E_NUM; e++) {
      if (taken[e] || !gmask[e / EPG]) continue;
      if (swb[e] > bv) { bv = swb[e]; best = e; }
    }
    taken[best] = true;
    idx[k] = best;
    wv[k] = sc[best];
    wsum += sc[best];
  }
  float inv = RSCALE / (wsum + 1e-20f);
  for (int k = 0; k < TOPK; k++) {
    tk_idx[t * TOPK + k] = idx[k];
    tk_w[t * TOPK + k] = wv[k] * inv;
    atomicAdd(&counts[idx[k]], 1);
  }
}

__global__ void scan_kernel(const int* __restrict__ counts, int* __restrict__ offsets,
                            int* __restrict__ cursor) {
  if (threadIdx.x == 0 && blockIdx.x == 0) {
    int acc = 0;
    for (int e = 0; e < E_NUM; e++) {
      offsets[e] = acc;
      cursor[e] = acc;
      acc += counts[e];
    }
    offsets[E_NUM] = acc;
  }
}

__global__ void scatter_kernel(const int* __restrict__ tk_idx, const float* __restrict__ tk_w,
                               int* __restrict__ cursor, int* __restrict__ pair_tok,
                               float* __restrict__ pair_w) {
  int t = blockIdx.x * blockDim.x + threadIdx.x;
  if (t >= T_TOK) return;
  for (int k = 0; k < TOPK; k++) {
    int e = tk_idx[t * TOPK + k];
    int p = atomicAdd(&cursor[e], 1);
    pair_tok[p] = t;
    pair_w[p] = tk_w[t * TOPK + k];
  }
}

// ---------- GEMM1: h = silu(X@W1^T) * (X@W3^T), gathered rows, bf16 out ----------
// X: [*, K] bf16 (rows via rowidx or identity). W1/W3: [N,K] row-major (+ e*wstride).
// Hout rows are base+m0+row (packed per-expert segments for routed case).

__global__ __launch_bounds__(256) void gemm1_kernel(
    const u16* __restrict__ X, const u16* __restrict__ W1, const u16* __restrict__ W3,
    u16* __restrict__ Hout, const int* __restrict__ rowidx, const int* __restrict__ offsets,
    const int* __restrict__ counts, int K, int N, int Mfixed, long wstride) {
  int e = blockIdx.z;
  int base = 0, M = Mfixed;
  if (counts) { M = counts[e]; base = offsets[e]; }
  int m0 = blockIdx.y * BM;
  if (m0 >= M) return;
  int n0 = blockIdx.x * BN;
  const u16* w1 = W1 + (long)e * wstride;
  const u16* w3 = W3 + (long)e * wstride;

  __shared__ __attribute__((aligned(16))) u16 sA[BM * BK];
  __shared__ __attribute__((aligned(16))) u16 sB1[BN * BK];
  __shared__ __attribute__((aligned(16))) u16 sB2[BN * BK];

  int tid = threadIdx.x;
  int col8 = (tid & 7) * 8;
  int row0 = tid >> 3;

  const u16* aptr[4];
#pragma unroll
  for (int c = 0; c < 4; c++) {
    int r = m0 + row0 + c * 32;
    int rr = (r < M) ? r : (M - 1);
    long tok = rowidx ? (long)rowidx[base + rr] : (long)rr;
    aptr[c] = X + tok * K + col8;
  }
  const u16* b1p = w1 + (long)(n0 + row0) * K + col8;
  const u16* b3p = w3 + (long)(n0 + row0) * K + col8;

  f32x4 acc1[4][4] = {};
  f32x4 acc2[4][4] = {};

  int lane = tid & 63;
  int wid = tid >> 6;
  int wm = (wid & 1) * 64;
  int wn = (wid >> 1) * 64;
  int lm = lane & 15;
  int lq = lane >> 4;

  for (int kt = 0; kt < K; kt += BK) {
#pragma unroll
    for (int c = 0; c < 4; c++) {
      gll16(aptr[c], &sA[(tid + c * 256) * 8]);
      gll16(b1p + (long)c * 32 * K, &sB1[(tid + c * 256) * 8]);
      gll16(b3p + (long)c * 32 * K, &sB2[(tid + c * 256) * 8]);
      aptr[c] += BK;
    }
    b1p += BK;
    b3p += BK;
    __syncthreads();
#pragma unroll
    for (int kk = 0; kk < 2; kk++) {
      short8 af[4], bf1[4], bf2[4];
#pragma unroll
      for (int mi = 0; mi < 4; mi++)
        af[mi] = *(const short8*)&sA[(wm + mi * 16 + lm) * BK + kk * 32 + lq * 8];
#pragma unroll
      for (int ni = 0; ni < 4; ni++) {
        bf1[ni] = *(const short8*)&sB1[(wn + ni * 16 + lm) * BK + kk * 32 + lq * 8];
        bf2[ni] = *(const short8*)&sB2[(wn + ni * 16 + lm) * BK + kk * 32 + lq * 8];
      }
#pragma unroll
      for (int mi = 0; mi < 4; mi++)
#pragma unroll
        for (int ni = 0; ni < 4; ni++) {
          acc1[mi][ni] = __builtin_amdgcn_mfma_f32_16x16x32_bf16(af[mi], bf1[ni], acc1[mi][ni], 0, 0, 0);
          acc2[mi][ni] = __builtin_amdgcn_mfma_f32_16x16x32_bf16(af[mi], bf2[ni], acc2[mi][ni], 0, 0, 0);
        }
    }
    __syncthreads();
  }

  int mrem = M - m0;
#pragma unroll
  for (int mi = 0; mi < 4; mi++) {
#pragma unroll
    for (int r = 0; r < 4; r++) {
      int row = wm + mi * 16 + lq * 4 + r;
      if (row >= mrem) continue;
      long orow = (long)(base + m0 + row) * N + n0 + wn + lm;
#pragma unroll
      for (int ni = 0; ni < 4; ni++) {
        float a = acc1[mi][ni][r];
        float u = acc2[mi][ni][r];
        float hv = (a / (1.0f + __expf(-a))) * u;
        Hout[orow + ni * 16] = f2bf(hv);
      }
    }
  }
}

// ---------- GEMM2: y = Hin @ W2^T, scale by combine weight, store/atomicAdd to out ----------

__global__ __launch_bounds__(256) void gemm2_kernel(
    const u16* __restrict__ Hin, const u16* __restrict__ W2, float* __restrict__ Out,
    const int* __restrict__ pair_tok, const float* __restrict__ pair_w,
    const int* __restrict__ offsets, const int* __restrict__ counts, int K, int N, int Mfixed,
    long wstride, int atom) {
  int e = blockIdx.z;
  int base = 0, M = Mfixed;
  if (counts) { M = counts[e]; base = offsets[e]; }
  int m0 = blockIdx.y * BM;
  if (m0 >= M) return;
  int n0 = blockIdx.x * BN;
  const u16* w2 = W2 + (long)e * wstride;

  __shared__ __attribute__((aligned(16))) u16 sA[BM * BK];
  __shared__ __attribute__((aligned(16))) u16 sB[BN * BK];

  int tid = threadIdx.x;
  int col8 = (tid & 7) * 8;
  int row0 = tid >> 3;

  const u16* ap[4];
#pragma unroll
  for (int c = 0; c < 4; c++) {
    int r = m0 + row0 + c * 32;
    int rr = (r < M) ? r : (M - 1);
    ap[c] = Hin + (long)(base + rr) * K + col8;
  }
  const u16* bp = w2 + (long)(n0 + row0) * K + col8;

  f32x4 acc[4][4] = {};

  int lane = tid & 63;
  int wid = tid >> 6;
  int wm = (wid & 1) * 64;
  int wn = (wid >> 1) * 64;
  int lm = lane & 15;
  int lq = lane >> 4;

  for (int kt = 0; kt < K; kt += BK) {
#pragma unroll
    for (int c = 0; c < 4; c++) {
      gll16(ap[c], &sA[(tid + c * 256) * 8]);
      gll16(bp + (long)c * 32 * K, &sB[(tid + c * 256) * 8]);
      ap[c] += BK;
    }
    bp += BK;
    __syncthreads();
#pragma unroll
    for (int kk = 0; kk < 2; kk++) {
      short8 af[4], bfr[4];
#pragma unroll
      for (int mi = 0; mi < 4; mi++)
        af[mi] = *(const short8*)&sA[(wm + mi * 16 + lm) * BK + kk * 32 + lq * 8];
#pragma unroll
      for (int ni = 0; ni < 4; ni++)
        bfr[ni] = *(const short8*)&sB[(wn + ni * 16 + lm) * BK + kk * 32 + lq * 8];
#pragma unroll
      for (int mi = 0; mi < 4; mi++)
#pragma unroll
        for (int ni = 0; ni < 4; ni++)
          acc[mi][ni] = __builtin_amdgcn_mfma_f32_16x16x32_bf16(af[mi], bfr[ni], acc[mi][ni], 0, 0, 0);
    }
    __syncthreads();
  }

  int mrem = M - m0;
#pragma unroll
  for (int mi = 0; mi < 4; mi++) {
#pragma unroll
    for (int r = 0; r < 4; r++) {
      int row = wm + mi * 16 + lq * 4 + r;
      if (row >= mrem) continue;
      int grow = base + m0 + row;
      int trow;
      float scale;
      if (pair_tok) { trow = pair_tok[grow]; scale = pair_w[grow]; }
      else { trow = grow; scale = 1.0f; }
      long obase = (long)trow * N + n0 + wn + lm;
#pragma unroll
      for (int ni = 0; ni < 4; ni++) {
        float v = acc[mi][ni][r] * scale;
        if (atom) atomicAdd(&Out[obase + ni * 16], v);
        else Out[obase + ni * 16] = v;
      }
    }
  }
}

// ---------- launch ----------

extern "C" void kernel_launch(void* const* d_in, const int* in_sizes, int n_in, void* d_out,
                              int out_size, void* d_ws, size_t ws_size, hipStream_t stream) {
  const float* x = (const float*)d_in[0];
  const float* gate_w = (const float*)d_in[1];
  const float* e_bias = (const float*)d_in[2];
  const float* w1 = (const float*)d_in[3];
  const float* w3 = (const float*)d_in[4];
  const float* w2 = (const float*)d_in[5];
  const float* sw1 = (const float*)d_in[6];
  const float* sw3 = (const float*)d_in[7];
  const float* sw2 = (const float*)d_in[8];
  float* out = (float*)d_out;

  char* p = (char*)d_ws;
  auto alloc = [&](size_t bytes) {
    char* r = p;
    p += (bytes + 255) & ~(size_t)255;
    return r;
  };
  u16* xb = (u16*)alloc((size_t)T_TOK * H_DIM * 2);
  u16* w1b = (u16*)alloc((size_t)E_NUM * I_DIM * H_DIM * 2);
  u16* w3b = (u16*)alloc((size_t)E_NUM * I_DIM * H_DIM * 2);
  u16* w2b = (u16*)alloc((size_t)E_NUM * H_DIM * I_DIM * 2);
  u16* sw1b = (u16*)alloc((size_t)IS_DIM * H_DIM * 2);
  u16* sw3b = (u16*)alloc((size_t)IS_DIM * H_DIM * 2);
  u16* sw2b = (u16*)alloc((size_t)H_DIM * IS_DIM * 2);
  float* logits = (float*)alloc((size_t)T_TOK * E_NUM * 4);
  int* tk_idx = (int*)alloc((size_t)T_TOK * TOPK * 4);
  float* tk_w = (float*)alloc((size_t)T_TOK * TOPK * 4);
  int* counts = (int*)alloc(256);
  int* offsets = (int*)alloc(256);
  int* cursor = (int*)alloc(256);
  int* pair_tok = (int*)alloc((size_t)NPAIR * 4);
  float* pair_w = (float*)alloc((size_t)NPAIR * 4);
  u16* h_r = (u16*)alloc((size_t)NPAIR * I_DIM * 2);
  u16* h_s = (u16*)alloc((size_t)T_TOK * IS_DIM * 2);

  zero_kernel<<<1, 64, 0, stream>>>(counts);

  cvt_kernel<<<1024, 256, 0, stream>>>(x, xb, T_TOK * H_DIM / 4);
  cvt_kernel<<<4096, 256, 0, stream>>>(w1, w1b, E_NUM * I_DIM * H_DIM / 4);
  cvt_kernel<<<4096, 256, 0, stream>>>(w3, w3b, E_NUM * I_DIM * H_DIM / 4);
  cvt_kernel<<<4096, 256, 0, stream>>>(w2, w2b, E_NUM * H_DIM * I_DIM / 4);
  cvt_kernel<<<512, 256, 0, stream>>>(sw1, sw1b, IS_DIM * H_DIM / 4);
  cvt_kernel<<<512, 256, 0, stream>>>(sw3, sw3b, IS_DIM * H_DIM / 4);
  cvt_kernel<<<512, 256, 0, stream>>>(sw2, sw2b, H_DIM * IS_DIM / 4);

  router_kernel<<<T_TOK, 256, 0, stream>>>(x, gate_w, logits);
  routing_kernel<<<T_TOK / 256, 256, 0, stream>>>(logits, e_bias, tk_idx, tk_w, counts);
  scan_kernel<<<1, 1, 0, stream>>>(counts, offsets, cursor);
  scatter_kernel<<<T_TOK / 256, 256, 0, stream>>>(tk_idx, tk_w, cursor, pair_tok, pair_w);

  // shared MLP: writes every element of out (plain store) -> initializes d_out
  gemm1_kernel<<<dim3(IS_DIM / BN, T_TOK / BM, 1), 256, 0, stream>>>(
      xb, sw1b, sw3b, h_s, nullptr, nullptr, nullptr, H_DIM, IS_DIM, T_TOK, 0);
  gemm2_kernel<<<dim3(H_DIM / BN, T_TOK / BM, 1), 256, 0, stream>>>(
      h_s, sw2b, out, nullptr, nullptr, nullptr, nullptr, IS_DIM, H_DIM, T_TOK, 0, 0);

  // routed experts: grouped GEMMs over expert-sorted pair list, atomic combine
  gemm1_kernel<<<dim3(I_DIM / BN, T_TOK / BM, E_NUM), 256, 0, stream>>>(
      xb, w1b, w3b, h_r, pair_tok, offsets, counts, H_DIM, I_DIM, 0, (long)I_DIM * H_DIM);
  gemm2_kernel<<<dim3(H_DIM / BN, T_TOK / BM, E_NUM), 256, 0, stream>>>(
      h_r, w2b, out, pair_tok, pair_w, offsets, counts, I_DIM, H_DIM, 0, (long)H_DIM * I_DIM, 1);
}